// Round 2
// baseline (79.833 us; speedup 1.0000x reference)
//
#include <hip/hip_runtime.h>
#include <math.h>

// S4D kernel: K[h,l] = 2 * Re( sum_n C_n * exp(dtA_n * l) ), H=512, NH=32, L=8192.
// Factorization: l = 64*l1 + l0, exp(dtA*l) = exp(dtA*64*l1) * exp(dtA*l0).
// One block per h. LDS tables: D[n][l1] = Ccoef_n * exp(dtA_n*64*l1) (32x128 cplx,
// imag part stored NEGATED), E0[n][l0] = exp(dtA_n*l0) (32x64 cplx).
// K[l1*64+l0] = Dr[n][l1]*E0r[n][l0] + DiNeg[n][l1]*E0i[n][l0], summed over n, x2.

constexpr int H_DIM = 512;
constexpr int NH    = 32;
constexpr int LLEN  = 8192;
constexpr int L0N   = 64;    // inner factor
constexpr int L1N   = 128;   // outer factor: LLEN = L0N * L1N

constexpr double INV_2PI = 0.15915494309189535;

// Component-wise FMA on float4 — all constant component access, registers only.
__device__ __forceinline__ float4 fma4(float s, float4 v, float4 a) {
    a.x = fmaf(s, v.x, a.x);
    a.y = fmaf(s, v.y, a.y);
    a.z = fmaf(s, v.z, a.z);
    a.w = fmaf(s, v.w, a.w);
    return a;
}

__global__ __launch_bounds__(256) void s4d_kernel(
    const float* __restrict__ C_real,
    const float* __restrict__ C_imag,
    const float* __restrict__ log_dt,
    const float* __restrict__ log_a_real,
    const float* __restrict__ A_imag,
    float* __restrict__ K)
{
    __shared__ float E0r[NH][L0N];
    __shared__ float E0i[NH][L0N];
    __shared__ float Dr[NH][L1N];
    __shared__ float Dni[NH][L1N];   // negated imag
    __shared__ float  s_a[NH];       // dtA real part (decay rate)
    __shared__ float  s_cr[NH];      // C coefficient real
    __shared__ float  s_ci[NH];      // C coefficient imag
    __shared__ double s_rev[NH];     // dtA imag / (2*pi): revolutions per unit t

    const int h   = blockIdx.x;
    const int tid = threadIdx.x;

    // ---- Phase 1: per-n scalars (first 32 threads) ----
    if (tid < NH) {
        const int n = tid;
        const float dt   = expf(log_dt[h]);
        const float a_re = -expf(log_a_real[h * NH + n]);  // A real
        const float a_im = A_imag[h * NH + n];             // A imag
        const float da_re = a_re * dt;                     // dtA real
        const float da_im = a_im * dt;                     // dtA imag
        // C = (Cr + i*Ci) * (exp(dtA) - 1) / A
        const float er = expf(da_re);
        float sn, cs;
        sincosf(da_im, &sn, &cs);
        const float num_re = er * cs - 1.0f;
        const float num_im = er * sn;
        const float inv    = 1.0f / (a_re * a_re + a_im * a_im);
        const float q_re = (num_re * a_re + num_im * a_im) * inv;
        const float q_im = (num_im * a_re - num_re * a_im) * inv;
        const float cr = C_real[h * NH + n];
        const float ci = C_imag[h * NH + n];
        s_cr[n]  = cr * q_re - ci * q_im;
        s_ci[n]  = cr * q_im + ci * q_re;
        s_a[n]   = da_re;
        s_rev[n] = (double)da_im * INV_2PI;
    }
    __syncthreads();

    // ---- Phase 2a: E0 table (32*64 = 2048 entries) ----
    for (int e = tid; e < NH * L0N; e += 256) {
        const int n = e >> 6;
        const int t = e & 63;
        const double rev = s_rev[n] * (double)t;
        const float  fr  = (float)(rev - floor(rev));   // [0,1) revolutions
        const float  mag = expf(s_a[n] * (float)t);
        E0r[n][t] = mag * __builtin_amdgcn_cosf(fr);    // v_cos_f32: revolutions input
        E0i[n][t] = mag * __builtin_amdgcn_sinf(fr);
    }

    // ---- Phase 2b: D table (32*128 = 4096 entries), folds in C coeff + sign ----
    for (int e = tid; e < NH * L1N; e += 256) {
        const int n  = e >> 7;
        const int l1 = e & 127;
        const int t  = l1 << 6;  // 64*l1
        const double rev = s_rev[n] * (double)t;
        const float  fr  = (float)(rev - floor(rev));
        const float  mag = expf(s_a[n] * (float)t);
        const float  wr  = mag * __builtin_amdgcn_cosf(fr);
        const float  wi  = mag * __builtin_amdgcn_sinf(fr);
        Dr[n][l1]  = s_cr[n] * wr - s_ci[n] * wi;
        Dni[n][l1] = -(s_cr[n] * wi + s_ci[n] * wr);
    }
    __syncthreads();

    // ---- Phase 3: main compute. Thread tile = 4 (l1) x 8 (l0). ----
    const int g1  = tid >> 3;    // 0..31
    const int g0  = tid & 7;     // 0..7
    const int l1b = g1 * 4;
    const int l0b = g0 * 8;

    float4 aA0 = make_float4(0.f, 0.f, 0.f, 0.f), aB0 = aA0;
    float4 aA1 = aA0, aB1 = aA0;
    float4 aA2 = aA0, aB2 = aA0;
    float4 aA3 = aA0, aB3 = aA0;

#pragma unroll 4
    for (int n = 0; n < NH; ++n) {
        const float4 dr = *reinterpret_cast<const float4*>(&Dr[n][l1b]);
        const float4 di = *reinterpret_cast<const float4*>(&Dni[n][l1b]);
        const float4 ea = *reinterpret_cast<const float4*>(&E0r[n][l0b]);
        const float4 eb = *reinterpret_cast<const float4*>(&E0r[n][l0b + 4]);
        const float4 fa = *reinterpret_cast<const float4*>(&E0i[n][l0b]);
        const float4 fb = *reinterpret_cast<const float4*>(&E0i[n][l0b + 4]);
        aA0 = fma4(dr.x, ea, aA0); aA0 = fma4(di.x, fa, aA0);
        aB0 = fma4(dr.x, eb, aB0); aB0 = fma4(di.x, fb, aB0);
        aA1 = fma4(dr.y, ea, aA1); aA1 = fma4(di.y, fa, aA1);
        aB1 = fma4(dr.y, eb, aB1); aB1 = fma4(di.y, fb, aB1);
        aA2 = fma4(dr.z, ea, aA2); aA2 = fma4(di.z, fa, aA2);
        aB2 = fma4(dr.z, eb, aB2); aB2 = fma4(di.z, fb, aB2);
        aA3 = fma4(dr.w, ea, aA3); aA3 = fma4(di.w, fa, aA3);
        aB3 = fma4(dr.w, eb, aB3); aB3 = fma4(di.w, fb, aB3);
    }

    // ---- Store: 4 rows x 8 contiguous floats (two float4 per row) ----
    float* base = K + (size_t)h * LLEN + l1b * L0N + l0b;
    {
        float4 o0 = make_float4(2.f * aA0.x, 2.f * aA0.y, 2.f * aA0.z, 2.f * aA0.w);
        float4 o1 = make_float4(2.f * aB0.x, 2.f * aB0.y, 2.f * aB0.z, 2.f * aB0.w);
        reinterpret_cast<float4*>(base)[0] = o0;
        reinterpret_cast<float4*>(base)[1] = o1;
    }
    {
        float4 o0 = make_float4(2.f * aA1.x, 2.f * aA1.y, 2.f * aA1.z, 2.f * aA1.w);
        float4 o1 = make_float4(2.f * aB1.x, 2.f * aB1.y, 2.f * aB1.z, 2.f * aB1.w);
        reinterpret_cast<float4*>(base + L0N)[0] = o0;
        reinterpret_cast<float4*>(base + L0N)[1] = o1;
    }
    {
        float4 o0 = make_float4(2.f * aA2.x, 2.f * aA2.y, 2.f * aA2.z, 2.f * aA2.w);
        float4 o1 = make_float4(2.f * aB2.x, 2.f * aB2.y, 2.f * aB2.z, 2.f * aB2.w);
        reinterpret_cast<float4*>(base + 2 * L0N)[0] = o0;
        reinterpret_cast<float4*>(base + 2 * L0N)[1] = o1;
    }
    {
        float4 o0 = make_float4(2.f * aA3.x, 2.f * aA3.y, 2.f * aA3.z, 2.f * aA3.w);
        float4 o1 = make_float4(2.f * aB3.x, 2.f * aB3.y, 2.f * aB3.z, 2.f * aB3.w);
        reinterpret_cast<float4*>(base + 3 * L0N)[0] = o0;
        reinterpret_cast<float4*>(base + 3 * L0N)[1] = o1;
    }
}

extern "C" void kernel_launch(void* const* d_in, const int* in_sizes, int n_in,
                              void* d_out, int out_size, void* d_ws, size_t ws_size,
                              hipStream_t stream) {
    const float* C_real     = (const float*)d_in[0];
    const float* C_imag     = (const float*)d_in[1];
    const float* log_dt     = (const float*)d_in[2];
    const float* log_a_real = (const float*)d_in[3];
    const float* A_imag     = (const float*)d_in[4];
    float* K = (float*)d_out;
    hipLaunchKernelGGL(s4d_kernel, dim3(H_DIM), dim3(256), 0, stream,
                       C_real, C_imag, log_dt, log_a_real, A_imag, K);
}